// Round 4
// baseline (393.107 us; speedup 1.0000x reference)
//
#include <hip/hip_runtime.h>

#define E 512
#define Hh 8
#define Dd 64
#define Ss 4096
#define Bb 2

typedef _Float16 f16;
typedef __attribute__((ext_vector_type(4))) _Float16 f16x4;
typedef __attribute__((ext_vector_type(8))) _Float16 f16x8;
typedef __attribute__((ext_vector_type(4))) float f32x4;

// ---------------- convert emb fp32 -> f16 ----------------
__global__ __launch_bounds__(256) void cvt_emb_kernel(const float* __restrict__ in,
                                                      f16* __restrict__ out) {
    int i = (blockIdx.x * 256 + threadIdx.x) * 8;
    float4 a = *(const float4*)(in + i);
    float4 b = *(const float4*)(in + i + 4);
    f16x8 o;
    o[0] = (f16)a.x; o[1] = (f16)a.y; o[2] = (f16)a.z; o[3] = (f16)a.w;
    o[4] = (f16)b.x; o[5] = (f16)b.y; o[6] = (f16)b.z; o[7] = (f16)b.w;
    *(f16x8*)(out + i) = o;
}

// ------------- transpose weights -> Wt[n][k] f16 -------------
__global__ __launch_bounds__(64) void cvt_w_kernel(const float* __restrict__ wq,
                                                   const float* __restrict__ wk,
                                                   const float* __restrict__ wv,
                                                   const float* __restrict__ wo,
                                                   f16* __restrict__ wtqkv,
                                                   f16* __restrict__ wto) {
    int n = blockIdx.x;      // 0..2047
    int t = threadIdx.x;     // 0..63
    const float* src;
    f16* dst;
    int col = n & 511;
    if (n < 1536) {
        int which = n >> 9;
        src = (which == 0) ? wq : (which == 1) ? wk : wv;
        dst = wtqkv + (size_t)n * E;
    } else {
        src = wo;
        dst = wto + (size_t)(n - 1536) * E;
    }
    int k0 = t * 8;
    f16x8 o;
#pragma unroll
    for (int j = 0; j < 8; ++j) o[j] = (f16)src[(size_t)(k0 + j) * E + col];
    *(f16x8*)(dst + k0) = o;
}

// ---------------- QKV projection GEMM ----------------
#define LDP 40

__global__ __launch_bounds__(256) void gemm_qkv_kernel(
    const f16* __restrict__ A, const f16* __restrict__ Wt,
    const float* __restrict__ bq, const float* __restrict__ bk,
    const float* __restrict__ bv,
    f16* __restrict__ Qb, f16* __restrict__ Kb, f16* __restrict__ Vt) {
    __shared__ f16 As[128 * LDP];
    __shared__ f16 Bs[128 * LDP];
    int tid = threadIdx.x;
    int m0 = blockIdx.x * 128, n0 = blockIdx.y * 128;
    int w = tid >> 6, lane = tid & 63;
    int wr = w >> 1, wc = w & 1;
    int lgrp = lane >> 4, l16 = lane & 15;
    f32x4 acc[4][4];
#pragma unroll
    for (int i = 0; i < 4; ++i)
#pragma unroll
        for (int j = 0; j < 4; ++j) acc[i][j] = (f32x4){0.f, 0.f, 0.f, 0.f};

    for (int kt = 0; kt < 16; ++kt) {
        int k0 = kt * 32;
        {
            int c = tid, row = c >> 2, seg = c & 3;
            *(f16x8*)&As[row * LDP + seg * 8] = *(const f16x8*)&A[(size_t)(m0 + row) * E + k0 + seg * 8];
            *(f16x8*)&Bs[row * LDP + seg * 8] = *(const f16x8*)&Wt[(size_t)(n0 + row) * E + k0 + seg * 8];
            c = tid + 256; row = c >> 2; seg = c & 3;
            *(f16x8*)&As[row * LDP + seg * 8] = *(const f16x8*)&A[(size_t)(m0 + row) * E + k0 + seg * 8];
            *(f16x8*)&Bs[row * LDP + seg * 8] = *(const f16x8*)&Wt[(size_t)(n0 + row) * E + k0 + seg * 8];
        }
        __syncthreads();
        f16x8 af[4], bfr[4];
#pragma unroll
        for (int mi = 0; mi < 4; ++mi)
            af[mi] = *(const f16x8*)&As[(wr * 64 + mi * 16 + l16) * LDP + lgrp * 8];
#pragma unroll
        for (int ni = 0; ni < 4; ++ni)
            bfr[ni] = *(const f16x8*)&Bs[(wc * 64 + ni * 16 + l16) * LDP + lgrp * 8];
#pragma unroll
        for (int mi = 0; mi < 4; ++mi)
#pragma unroll
            for (int ni = 0; ni < 4; ++ni)
                acc[mi][ni] = __builtin_amdgcn_mfma_f32_16x16x32_f16(af[mi], bfr[ni], acc[mi][ni], 0, 0, 0);
        __syncthreads();
    }
#pragma unroll
    for (int mi = 0; mi < 4; ++mi) {
#pragma unroll
        for (int ni = 0; ni < 4; ++ni) {
#pragma unroll
            for (int r = 0; r < 4; ++r) {
                int gm = m0 + wr * 64 + mi * 16 + lgrp * 4 + r;
                int gn = n0 + wc * 64 + ni * 16 + l16;
                int which = gn >> 9, e = gn & 511;
                int h = e >> 6, d = e & 63;
                int b = gm >> 12, s = gm & 4095;
                float v = acc[mi][ni][r];
                if (which == 0) {
                    // fold 1/sqrt(64) AND log2(e) into Q so attention works in exp2 domain
                    v = (v + bq[e]) * 0.180336880111f;
                    Qb[(size_t)((b * Hh + h) * Ss + s) * Dd + d] = (f16)v;
                } else if (which == 1) {
                    v += bk[e];
                    Kb[(size_t)((b * Hh + h) * Ss + s) * Dd + d] = (f16)v;
                } else {
                    v += bv[e];
                    Vt[(size_t)((b * Hh + h) * Dd + d) * Ss + s] = (f16)v;
                }
            }
        }
    }
}

// ---------------- causal flash attention (swapped QK^T, K ping-pong prefetch) ----------------
// grid (32, B*H), block 256 = 4 waves. Wave owns q-tile = 127-(4*bx+w), QBLK=32, KVBLK=64.
// Swapped QK^T: mfma(K, Q) -> S^T; lane holds q = lane&15 (+16*nf), kv = 4*(lane>>4)+r (+16*mf).
// K(t+1) is register-prefetched (ping-pong kfA/kfB) during tile t's softmax+PV so its
// L2/L3 latency is hidden; V(t) is issued at tile top and consumed only by PV (~400cyc later).
__global__ __launch_bounds__(256, 2) void attn_kernel(const f16* __restrict__ Qb,
                                                      const f16* __restrict__ Kb,
                                                      const f16* __restrict__ Vt,
                                                      f16* __restrict__ attn) {
    __shared__ __align__(16) f16 Pl[4][32 * 64];
    __shared__ __align__(16) float SCL[4][32];
    int tid = threadIdx.x;
    int w = tid >> 6, lane = tid & 63;
    int g = lane >> 4, l16 = lane & 15;
    int bh = blockIdx.y;
    int tile = 127 - (blockIdx.x * 4 + w);   // heavy tiles dispatch first
    int q0 = tile * 32;
    const f16* Qp = Qb + (size_t)bh * Ss * Dd;
    const f16* Kp = Kb + (size_t)bh * Ss * Dd;
    const f16* Vp = Vt + (size_t)bh * Dd * Ss;
    f16* Pw = Pl[w];
    float* sclw = SCL[w];

    // Q fragments (B-operand): col = q = l16 (+16*nf), k = d = kc*32 + g*8 + j
    f16x8 qf[2][2];
#pragma unroll
    for (int nf = 0; nf < 2; ++nf)
#pragma unroll
        for (int kc = 0; kc < 2; ++kc)
            qf[nf][kc] = *(const f16x8*)&Qp[(size_t)(q0 + nf * 16 + l16) * Dd + kc * 32 + g * 8];

    f32x4 o[2][4];
#pragma unroll
    for (int mq = 0; mq < 2; ++mq)
#pragma unroll
        for (int nd = 0; nd < 4; ++nd) o[mq][nd] = (f32x4){0.f, 0.f, 0.f, 0.f};
    float m_run[2] = {-INFINITY, -INFINITY}, l_run[2] = {0.f, 0.f};

    const int count = (tile >> 1) + 1;  // KV tiles of 64 covering kv <= q0+31
    int t = 0;

    auto load_k = [&](f16x8 (&dst)[4][2], int n0) {
#pragma unroll
        for (int mf = 0; mf < 4; ++mf)
#pragma unroll
            for (int kc = 0; kc < 2; ++kc)
                dst[mf][kc] = *(const f16x8*)&Kp[(size_t)(n0 + mf * 16 + l16) * Dd + kc * 32 + g * 8];
    };

    auto tile_body = [&](f16x8 (&kf)[4][2], f16x8 (&kfn)[4][2]) {
        int n0 = t << 6;
        bool last = (t == count - 1);
        // V fragments (B-operand for PV): col = d = l16 (+16*nd), k = kv contiguous
        f16x8 vf[4][2];
#pragma unroll
        for (int nd = 0; nd < 4; ++nd)
#pragma unroll
            for (int kc = 0; kc < 2; ++kc)
                vf[nd][kc] = *(const f16x8*)&Vp[(size_t)(nd * 16 + l16) * Ss + n0 + kc * 32 + g * 8];

        f32x4 s_[4][2];
#pragma unroll
        for (int mf = 0; mf < 4; ++mf)
#pragma unroll
            for (int nf = 0; nf < 2; ++nf) s_[mf][nf] = (f32x4){0.f, 0.f, 0.f, 0.f};
        __builtin_amdgcn_s_setprio(1);
#pragma unroll
        for (int kc = 0; kc < 2; ++kc)
#pragma unroll
            for (int mf = 0; mf < 4; ++mf)
#pragma unroll
                for (int nf = 0; nf < 2; ++nf)
                    s_[mf][nf] = __builtin_amdgcn_mfma_f32_16x16x32_f16(kf[mf][kc], qf[nf][kc], s_[mf][nf], 0, 0, 0);
        __builtin_amdgcn_s_setprio(0);

        // prefetch next K tile while softmax+PV run (hides L2/L3 latency)
        if (!last) load_k(kfn, n0 + 64);

        if (last) {  // only the diagonal tile masks
#pragma unroll
            for (int mf = 0; mf < 4; ++mf)
#pragma unroll
                for (int nf = 0; nf < 2; ++nf)
#pragma unroll
                    for (int r = 0; r < 4; ++r) {
                        int kv = n0 + mf * 16 + 4 * g + r;
                        int qq = q0 + nf * 16 + l16;
                        if (kv > qq) s_[mf][nf][r] = -INFINITY;
                    }
        }

        float scl2[2];
#pragma unroll
        for (int nf = 0; nf < 2; ++nf) {
            // tree max over the 16 in-lane values
            float a0 = fmaxf(fmaxf(s_[0][nf][0], s_[0][nf][1]), fmaxf(s_[0][nf][2], s_[0][nf][3]));
            float a1 = fmaxf(fmaxf(s_[1][nf][0], s_[1][nf][1]), fmaxf(s_[1][nf][2], s_[1][nf][3]));
            float a2 = fmaxf(fmaxf(s_[2][nf][0], s_[2][nf][1]), fmaxf(s_[2][nf][2], s_[2][nf][3]));
            float a3 = fmaxf(fmaxf(s_[3][nf][0], s_[3][nf][1]), fmaxf(s_[3][nf][2], s_[3][nf][3]));
            float mx = fmaxf(fmaxf(a0, a1), fmaxf(a2, a3));
            mx = fmaxf(mx, __shfl_xor(mx, 16));
            mx = fmaxf(mx, __shfl_xor(mx, 32));
            float mn = fmaxf(m_run[nf], mx);
            float sc = exp2f(m_run[nf] - mn);
            float ps[4];
#pragma unroll
            for (int mf = 0; mf < 4; ++mf) {
                float p0 = exp2f(s_[mf][nf][0] - mn);
                float p1 = exp2f(s_[mf][nf][1] - mn);
                float p2 = exp2f(s_[mf][nf][2] - mn);
                float p3 = exp2f(s_[mf][nf][3] - mn);
                s_[mf][nf][0] = p0; s_[mf][nf][1] = p1;
                s_[mf][nf][2] = p2; s_[mf][nf][3] = p3;
                ps[mf] = (p0 + p1) + (p2 + p3);
            }
            float ss = (ps[0] + ps[1]) + (ps[2] + ps[3]);
            ss += __shfl_xor(ss, 16);
            ss += __shfl_xor(ss, 32);
            l_run[nf] = l_run[nf] * sc + ss;
            m_run[nf] = mn;
            scl2[nf] = sc;
        }

        // P -> LDS [row=q 32][col=kv 64] f16, XOR-swizzled (row stride 128B)
#pragma unroll
        for (int nf = 0; nf < 2; ++nf) {
            int row = nf * 16 + l16;
            char* base = (char*)Pw + row * 128;
            int swz = (row & 7) << 4;
#pragma unroll
            for (int mf = 0; mf < 4; ++mf) {
                f16x4 ph;
#pragma unroll
                for (int r = 0; r < 4; ++r) ph[r] = (f16)s_[mf][nf][r];
                *(f16x4*)(base + ((mf * 32 + g * 8) ^ swz)) = ph;
            }
        }
        if (lane < 16) { sclw[l16] = scl2[0]; sclw[16 + l16] = scl2[1]; }
        asm volatile("s_waitcnt lgkmcnt(0)" ::: "memory");
        __builtin_amdgcn_sched_barrier(0);

        // rescale O by per-q factor (broadcast via LDS, q = mq*16+4g+r)
        f32x4 sr[2];
#pragma unroll
        for (int mq = 0; mq < 2; ++mq) sr[mq] = *(const f32x4*)&sclw[mq * 16 + 4 * g];
#pragma unroll
        for (int mq = 0; mq < 2; ++mq)
#pragma unroll
            for (int nd = 0; nd < 4; ++nd)
#pragma unroll
                for (int r = 0; r < 4; ++r) o[mq][nd][r] *= sr[mq][r];

        // P A-frags: row = q = l16 (+16*mq), k = kv = kc*32+g*8+j (same swizzle)
        f16x8 pa[2][2];
#pragma unroll
        for (int mq = 0; mq < 2; ++mq) {
            int row = mq * 16 + l16;
            const char* base = (const char*)Pw + row * 128;
            int swz = (row & 7) << 4;
#pragma unroll
            for (int kc = 0; kc < 2; ++kc)
                pa[mq][kc] = *(const f16x8*)(base + ((kc * 64 + g * 16) ^ swz));
        }
        __builtin_amdgcn_s_setprio(1);
#pragma unroll
        for (int kc = 0; kc < 2; ++kc)
#pragma unroll
            for (int mq = 0; mq < 2; ++mq)
#pragma unroll
                for (int nd = 0; nd < 4; ++nd)
                    o[mq][nd] = __builtin_amdgcn_mfma_f32_16x16x32_f16(pa[mq][kc], vf[nd][kc], o[mq][nd], 0, 0, 0);
        __builtin_amdgcn_s_setprio(0);
    };

    f16x8 kfA[4][2], kfB[4][2];
    load_k(kfA, 0);
    while (true) {
        tile_body(kfA, kfB);
        if (++t == count) break;
        tile_body(kfB, kfA);
        if (++t == count) break;
    }

    // final 1/l, redistributed q->(g,r) via LDS
    if (lane < 16) { sclw[l16] = l_run[0]; sclw[16 + l16] = l_run[1]; }
    asm volatile("s_waitcnt lgkmcnt(0)" ::: "memory");
    __builtin_amdgcn_sched_barrier(0);
    int b = bh >> 3, h = bh & 7;
#pragma unroll
    for (int mq = 0; mq < 2; ++mq) {
        f32x4 lr = *(const f32x4*)&sclw[mq * 16 + 4 * g];
#pragma unroll
        for (int r = 0; r < 4; ++r) {
            float inv = 1.f / lr[r];
            int srow = q0 + mq * 16 + 4 * g + r;
#pragma unroll
            for (int nd = 0; nd < 4; ++nd)
                attn[(size_t)(b * Ss + srow) * E + h * 64 + nd * 16 + l16] = (f16)(o[mq][nd][r] * inv);
        }
    }
}

// ---------------- output projection + bias + residual ----------------
__global__ __launch_bounds__(256) void gemm_out_kernel(
    const f16* __restrict__ A, const f16* __restrict__ Wt,
    const float* __restrict__ bo, const float* __restrict__ emb,
    float* __restrict__ xout) {
    __shared__ f16 As[128 * LDP];
    __shared__ f16 Bs[128 * LDP];
    int tid = threadIdx.x;
    int m0 = blockIdx.x * 128, n0 = blockIdx.y * 128;
    int w = tid >> 6, lane = tid & 63;
    int wr = w >> 1, wc = w & 1;
    int lgrp = lane >> 4, l16 = lane & 15;
    f32x4 acc[4][4];
#pragma unroll
    for (int i = 0; i < 4; ++i)
#pragma unroll
        for (int j = 0; j < 4; ++j) acc[i][j] = (f32x4){0.f, 0.f, 0.f, 0.f};

    for (int kt = 0; kt < 16; ++kt) {
        int k0 = kt * 32;
        {
            int c = tid, row = c >> 2, seg = c & 3;
            *(f16x8*)&As[row * LDP + seg * 8] = *(const f16x8*)&A[(size_t)(m0 + row) * E + k0 + seg * 8];
            *(f16x8*)&Bs[row * LDP + seg * 8] = *(const f16x8*)&Wt[(size_t)(n0 + row) * E + k0 + seg * 8];
            c = tid + 256; row = c >> 2; seg = c & 3;
            *(f16x8*)&As[row * LDP + seg * 8] = *(const f16x8*)&A[(size_t)(m0 + row) * E + k0 + seg * 8];
            *(f16x8*)&Bs[row * LDP + seg * 8] = *(const f16x8*)&Wt[(size_t)(n0 + row) * E + k0 + seg * 8];
        }
        __syncthreads();
        f16x8 af[4], bfr[4];
#pragma unroll
        for (int mi = 0; mi < 4; ++mi)
            af[mi] = *(const f16x8*)&As[(wr * 64 + mi * 16 + l16) * LDP + lgrp * 8];
#pragma unroll
        for (int ni = 0; ni < 4; ++ni)
            bfr[ni] = *(const f16x8*)&Bs[(wc * 64 + ni * 16 + l16) * LDP + lgrp * 8];
#pragma unroll
        for (int mi = 0; mi < 4; ++mi)
#pragma unroll
            for (int ni = 0; ni < 4; ++ni)
                acc[mi][ni] = __builtin_amdgcn_mfma_f32_16x16x32_f16(af[mi], bfr[ni], acc[mi][ni], 0, 0, 0);
        __syncthreads();
    }
#pragma unroll
    for (int mi = 0; mi < 4; ++mi) {
#pragma unroll
        for (int ni = 0; ni < 4; ++ni) {
#pragma unroll
            for (int r = 0; r < 4; ++r) {
                int gm = m0 + wr * 64 + mi * 16 + lgrp * 4 + r;
                int gn = n0 + wc * 64 + ni * 16 + l16;
                size_t idx = (size_t)gm * E + gn;
                xout[idx] = acc[mi][ni][r] + bo[gn] + emb[idx];
            }
        }
    }
}

// ---------------- LayerNorm ----------------
__global__ __launch_bounds__(256) void ln_kernel(const float* __restrict__ x,
                                                 const float* __restrict__ g,
                                                 const float* __restrict__ b,
                                                 float* __restrict__ out) {
    int w = threadIdx.x >> 6, lane = threadIdx.x & 63;
    int row = blockIdx.x * 4 + w;
    const float* xr = x + (size_t)row * E;
    int c0 = lane * 8;
    float4 a = *(const float4*)&xr[c0];
    float4 c = *(const float4*)&xr[c0 + 4];
    float s = a.x + a.y + a.z + a.w + c.x + c.y + c.z + c.w;
    float q = a.x * a.x + a.y * a.y + a.z * a.z + a.w * a.w +
              c.x * c.x + c.y * c.y + c.z * c.z + c.w * c.w;
#pragma unroll
    for (int m = 1; m <= 32; m <<= 1) {
        s += __shfl_xor(s, m);
        q += __shfl_xor(q, m);
    }
    float mean = s * (1.f / 512.f);
    float var = q * (1.f / 512.f) - mean * mean;
    float rstd = rsqrtf(var + 1e-5f);
    float4 o1, o2;
    o1.x = (a.x - mean) * rstd * g[c0 + 0] + b[c0 + 0];
    o1.y = (a.y - mean) * rstd * g[c0 + 1] + b[c0 + 1];
    o1.z = (a.z - mean) * rstd * g[c0 + 2] + b[c0 + 2];
    o1.w = (a.w - mean) * rstd * g[c0 + 3] + b[c0 + 3];
    o2.x = (c.x - mean) * rstd * g[c0 + 4] + b[c0 + 4];
    o2.y = (c.y - mean) * rstd * g[c0 + 5] + b[c0 + 5];
    o2.z = (c.z - mean) * rstd * g[c0 + 6] + b[c0 + 6];
    o2.w = (c.w - mean) * rstd * g[c0 + 7] + b[c0 + 7];
    *(float4*)&out[(size_t)row * E + c0] = o1;
    *(float4*)&out[(size_t)row * E + c0 + 4] = o2;
}

extern "C" void kernel_launch(void* const* d_in, const int* in_sizes, int n_in,
                              void* d_out, int out_size, void* d_ws, size_t ws_size,
                              hipStream_t stream) {
    const float* emb = (const float*)d_in[0];
    const float* wq = (const float*)d_in[1];
    const float* bq = (const float*)d_in[2];
    const float* wk = (const float*)d_in[3];
    const float* bk = (const float*)d_in[4];
    const float* wv = (const float*)d_in[5];
    const float* bv = (const float*)d_in[6];
    const float* wo = (const float*)d_in[7];
    const float* bo = (const float*)d_in[8];
    const float* ln_g = (const float*)d_in[9];
    const float* ln_b = (const float*)d_in[10];
    float* out = (float*)d_out;

    char* ws = (char*)d_ws;
    f16* embh  = (f16*)(ws);
    f16* wtqkv = (f16*)(ws + 8388608);
    f16* wto   = (f16*)(ws + 9961472);
    f16* Qb    = (f16*)(ws + 10485760);
    f16* Kb    = (f16*)(ws + 18874368);
    f16* Vt    = (f16*)(ws + 27262976);
    f16* attnb = (f16*)(ws + 35651584);
    float* xbuf = (float*)(ws + 10485760);  // overlaps Qb+Kb (dead after attention)

    cvt_emb_kernel<<<dim3(2048), dim3(256), 0, stream>>>(emb, embh);
    cvt_w_kernel<<<dim3(2048), dim3(64), 0, stream>>>(wq, wk, wv, wo, wtqkv, wto);
    gemm_qkv_kernel<<<dim3(64, 12), dim3(256), 0, stream>>>(embh, wtqkv, bq, bk, bv, Qb, Kb, Vt);
    attn_kernel<<<dim3(32, 16), dim3(256), 0, stream>>>(Qb, Kb, Vt, attnb);
    gemm_out_kernel<<<dim3(64, 4), dim3(256), 0, stream>>>(attnb, wto, bo, emb, xbuf);
    ln_kernel<<<dim3(2048), dim3(256), 0, stream>>>(xbuf, ln_g, ln_b, out);
}

// Round 7
// 313.621 us; speedup vs baseline: 1.2534x; 1.2534x over previous
//
#include <hip/hip_runtime.h>

#define E 512
#define Hh 8
#define Dd 64
#define Ss 4096
#define Bb 2

typedef _Float16 f16;
typedef __attribute__((ext_vector_type(4))) _Float16 f16x4;
typedef __attribute__((ext_vector_type(8))) _Float16 f16x8;
typedef __attribute__((ext_vector_type(4))) float f32x4;

// ---------------- convert emb fp32 -> f16 ----------------
__global__ __launch_bounds__(256) void cvt_emb_kernel(const float* __restrict__ in,
                                                      f16* __restrict__ out) {
    int i = (blockIdx.x * 256 + threadIdx.x) * 8;
    float4 a = *(const float4*)(in + i);
    float4 b = *(const float4*)(in + i + 4);
    f16x8 o;
    o[0] = (f16)a.x; o[1] = (f16)a.y; o[2] = (f16)a.z; o[3] = (f16)a.w;
    o[4] = (f16)b.x; o[5] = (f16)b.y; o[6] = (f16)b.z; o[7] = (f16)b.w;
    *(f16x8*)(out + i) = o;
}

// ------------- transpose weights -> Wt[n][k] f16 -------------
__global__ __launch_bounds__(64) void cvt_w_kernel(const float* __restrict__ wq,
                                                   const float* __restrict__ wk,
                                                   const float* __restrict__ wv,
                                                   const float* __restrict__ wo,
                                                   f16* __restrict__ wtqkv,
                                                   f16* __restrict__ wto) {
    int n = blockIdx.x;      // 0..2047
    int t = threadIdx.x;     // 0..63
    const float* src;
    f16* dst;
    int col = n & 511;
    if (n < 1536) {
        int which = n >> 9;
        src = (which == 0) ? wq : (which == 1) ? wk : wv;
        dst = wtqkv + (size_t)n * E;
    } else {
        src = wo;
        dst = wto + (size_t)(n - 1536) * E;
    }
    int k0 = t * 8;
    f16x8 o;
#pragma unroll
    for (int j = 0; j < 8; ++j) o[j] = (f16)src[(size_t)(k0 + j) * E + col];
    *(f16x8*)(dst + k0) = o;
}

// ---------------- QKV projection GEMM ----------------
#define LDP 40

__global__ __launch_bounds__(256) void gemm_qkv_kernel(
    const f16* __restrict__ A, const f16* __restrict__ Wt,
    const float* __restrict__ bq, const float* __restrict__ bk,
    const float* __restrict__ bv,
    f16* __restrict__ Qb, f16* __restrict__ Kb, f16* __restrict__ Vt) {
    __shared__ f16 As[128 * LDP];
    __shared__ f16 Bs[128 * LDP];
    int tid = threadIdx.x;
    int m0 = blockIdx.x * 128, n0 = blockIdx.y * 128;
    int w = tid >> 6, lane = tid & 63;
    int wr = w >> 1, wc = w & 1;
    int lgrp = lane >> 4, l16 = lane & 15;
    f32x4 acc[4][4];
#pragma unroll
    for (int i = 0; i < 4; ++i)
#pragma unroll
        for (int j = 0; j < 4; ++j) acc[i][j] = (f32x4){0.f, 0.f, 0.f, 0.f};

    for (int kt = 0; kt < 16; ++kt) {
        int k0 = kt * 32;
        {
            int c = tid, row = c >> 2, seg = c & 3;
            *(f16x8*)&As[row * LDP + seg * 8] = *(const f16x8*)&A[(size_t)(m0 + row) * E + k0 + seg * 8];
            *(f16x8*)&Bs[row * LDP + seg * 8] = *(const f16x8*)&Wt[(size_t)(n0 + row) * E + k0 + seg * 8];
            c = tid + 256; row = c >> 2; seg = c & 3;
            *(f16x8*)&As[row * LDP + seg * 8] = *(const f16x8*)&A[(size_t)(m0 + row) * E + k0 + seg * 8];
            *(f16x8*)&Bs[row * LDP + seg * 8] = *(const f16x8*)&Wt[(size_t)(n0 + row) * E + k0 + seg * 8];
        }
        __syncthreads();
        f16x8 af[4], bfr[4];
#pragma unroll
        for (int mi = 0; mi < 4; ++mi)
            af[mi] = *(const f16x8*)&As[(wr * 64 + mi * 16 + l16) * LDP + lgrp * 8];
#pragma unroll
        for (int ni = 0; ni < 4; ++ni)
            bfr[ni] = *(const f16x8*)&Bs[(wc * 64 + ni * 16 + l16) * LDP + lgrp * 8];
#pragma unroll
        for (int mi = 0; mi < 4; ++mi)
#pragma unroll
            for (int ni = 0; ni < 4; ++ni)
                acc[mi][ni] = __builtin_amdgcn_mfma_f32_16x16x32_f16(af[mi], bfr[ni], acc[mi][ni], 0, 0, 0);
        __syncthreads();
    }
#pragma unroll
    for (int mi = 0; mi < 4; ++mi) {
#pragma unroll
        for (int ni = 0; ni < 4; ++ni) {
#pragma unroll
            for (int r = 0; r < 4; ++r) {
                int gm = m0 + wr * 64 + mi * 16 + lgrp * 4 + r;
                int gn = n0 + wc * 64 + ni * 16 + l16;
                int which = gn >> 9, e = gn & 511;
                int h = e >> 6, d = e & 63;
                int b = gm >> 12, s = gm & 4095;
                float v = acc[mi][ni][r];
                if (which == 0) {
                    // fold 1/sqrt(64) AND log2(e) into Q so attention works in exp2 domain
                    v = (v + bq[e]) * 0.180336880111f;
                    Qb[(size_t)((b * Hh + h) * Ss + s) * Dd + d] = (f16)v;
                } else if (which == 1) {
                    v += bk[e];
                    Kb[(size_t)((b * Hh + h) * Ss + s) * Dd + d] = (f16)v;
                } else {
                    v += bv[e];
                    Vt[(size_t)((b * Hh + h) * Dd + d) * Ss + s] = (f16)v;
                }
            }
        }
    }
}

// ---------------- causal flash attention (swapped QK^T, single-wave blocks) ----------------
// grid (2048): block idx -> tile = 127-(idx>>4) (heavy first, LPT backfill), bh = idx&15.
// One wave (64 threads) per block, QBLK=32, KVBLK=64, ~4.2KB LDS -> TLP-limited only by VGPRs.
// Swapped QK^T: mfma(K, Q) -> S^T; lane holds q = lane&15 (+16*nf), kv = 4*(lane>>4)+r (+16*mf).
__global__ __launch_bounds__(64) void attn_kernel(const f16* __restrict__ Qb,
                                                  const f16* __restrict__ Kb,
                                                  const f16* __restrict__ Vt,
                                                  f16* __restrict__ attn) {
    __shared__ __align__(16) f16 Pw[32 * 64];
    __shared__ __align__(16) float sclw[32];
    int lane = threadIdx.x;
    int g = lane >> 4, l16 = lane & 15;
    int idx = blockIdx.x;
    int bh = idx & 15;
    int tile = 127 - (idx >> 4);   // heavy tiles dispatch first
    int q0 = tile * 32;
    const f16* Qp = Qb + (size_t)bh * Ss * Dd;
    const f16* Kp = Kb + (size_t)bh * Ss * Dd;
    const f16* Vp = Vt + (size_t)bh * Dd * Ss;

    // Q fragments (B-operand): col = q = l16 (+16*nf), k = d = kc*32 + g*8 + j
    f16x8 qf[2][2];
#pragma unroll
    for (int nf = 0; nf < 2; ++nf)
#pragma unroll
        for (int kc = 0; kc < 2; ++kc)
            qf[nf][kc] = *(const f16x8*)&Qp[(size_t)(q0 + nf * 16 + l16) * Dd + kc * 32 + g * 8];

    f32x4 o[2][4];
#pragma unroll
    for (int mq = 0; mq < 2; ++mq)
#pragma unroll
        for (int nd = 0; nd < 4; ++nd) o[mq][nd] = (f32x4){0.f, 0.f, 0.f, 0.f};
    float m_run[2] = {-INFINITY, -INFINITY}, l_run[2] = {0.f, 0.f};

    const int count = (tile >> 1) + 1;  // KV tiles of 64 covering kv <= q0+31
    for (int t = 0; t < count; ++t) {
        int n0 = t << 6;
        bool last = (t == count - 1);

        // K fragments (A-operand): row = kv = l16 (+16*mf), k = d
        f16x8 kf[4][2];
#pragma unroll
        for (int mf = 0; mf < 4; ++mf)
#pragma unroll
            for (int kc = 0; kc < 2; ++kc)
                kf[mf][kc] = *(const f16x8*)&Kp[(size_t)(n0 + mf * 16 + l16) * Dd + kc * 32 + g * 8];

        f32x4 s_[4][2];
#pragma unroll
        for (int mf = 0; mf < 4; ++mf)
#pragma unroll
            for (int nf = 0; nf < 2; ++nf) s_[mf][nf] = (f32x4){0.f, 0.f, 0.f, 0.f};
        __builtin_amdgcn_s_setprio(1);
#pragma unroll
        for (int kc = 0; kc < 2; ++kc)
#pragma unroll
            for (int mf = 0; mf < 4; ++mf)
#pragma unroll
                for (int nf = 0; nf < 2; ++nf)
                    s_[mf][nf] = __builtin_amdgcn_mfma_f32_16x16x32_f16(kf[mf][kc], qf[nf][kc], s_[mf][nf], 0, 0, 0);
        __builtin_amdgcn_s_setprio(0);

        // V fragments (B-operand for PV): col = d = l16 (+16*nd), k = kv contiguous.
        // Issued here so the ~200-400cyc L2 latency hides under mask+softmax.
        f16x8 vf[4][2];
#pragma unroll
        for (int nd = 0; nd < 4; ++nd)
#pragma unroll
            for (int kc = 0; kc < 2; ++kc)
                vf[nd][kc] = *(const f16x8*)&Vp[(size_t)(nd * 16 + l16) * Ss + n0 + kc * 32 + g * 8];

        if (last) {  // only the diagonal tile masks
#pragma unroll
            for (int mf = 0; mf < 4; ++mf)
#pragma unroll
                for (int nf = 0; nf < 2; ++nf)
#pragma unroll
                    for (int r = 0; r < 4; ++r) {
                        int kv = n0 + mf * 16 + 4 * g + r;
                        int qq = q0 + nf * 16 + l16;
                        if (kv > qq) s_[mf][nf][r] = -INFINITY;
                    }
        }

        float scl2[2];
#pragma unroll
        for (int nf = 0; nf < 2; ++nf) {
            // tree max over the 16 in-lane values
            float a0 = fmaxf(fmaxf(s_[0][nf][0], s_[0][nf][1]), fmaxf(s_[0][nf][2], s_[0][nf][3]));
            float a1 = fmaxf(fmaxf(s_[1][nf][0], s_[1][nf][1]), fmaxf(s_[1][nf][2], s_[1][nf][3]));
            float a2 = fmaxf(fmaxf(s_[2][nf][0], s_[2][nf][1]), fmaxf(s_[2][nf][2], s_[2][nf][3]));
            float a3 = fmaxf(fmaxf(s_[3][nf][0], s_[3][nf][1]), fmaxf(s_[3][nf][2], s_[3][nf][3]));
            float mx = fmaxf(fmaxf(a0, a1), fmaxf(a2, a3));
            mx = fmaxf(mx, __shfl_xor(mx, 16));
            mx = fmaxf(mx, __shfl_xor(mx, 32));
            float mn = fmaxf(m_run[nf], mx);
            float sc = exp2f(m_run[nf] - mn);
            float ps[4];
#pragma unroll
            for (int mf = 0; mf < 4; ++mf) {
                float p0 = exp2f(s_[mf][nf][0] - mn);
                float p1 = exp2f(s_[mf][nf][1] - mn);
                float p2 = exp2f(s_[mf][nf][2] - mn);
                float p3 = exp2f(s_[mf][nf][3] - mn);
                s_[mf][nf][0] = p0; s_[mf][nf][1] = p1;
                s_[mf][nf][2] = p2; s_[mf][nf][3] = p3;
                ps[mf] = (p0 + p1) + (p2 + p3);
            }
            float ss = (ps[0] + ps[1]) + (ps[2] + ps[3]);
            ss += __shfl_xor(ss, 16);
            ss += __shfl_xor(ss, 32);
            l_run[nf] = l_run[nf] * sc + ss;
            m_run[nf] = mn;
            scl2[nf] = sc;
        }

        // P -> LDS [row=q 32][col=kv 64] f16, XOR-swizzled (row stride 128B)
#pragma unroll
        for (int nf = 0; nf < 2; ++nf) {
            int row = nf * 16 + l16;
            char* base = (char*)Pw + row * 128;
            int swz = (row & 7) << 4;
#pragma unroll
            for (int mf = 0; mf < 4; ++mf) {
                f16x4 ph;
#pragma unroll
                for (int r = 0; r < 4; ++r) ph[r] = (f16)s_[mf][nf][r];
                *(f16x4*)(base + ((mf * 32 + g * 8) ^ swz)) = ph;
            }
        }
        if (lane < 16) { sclw[l16] = scl2[0]; sclw[16 + l16] = scl2[1]; }
        asm volatile("s_waitcnt lgkmcnt(0)" ::: "memory");
        __builtin_amdgcn_sched_barrier(0);

        // rescale O by per-q factor (broadcast via LDS, q = mq*16+4g+r)
        f32x4 sr[2];
#pragma unroll
        for (int mq = 0; mq < 2; ++mq) sr[mq] = *(const f32x4*)&sclw[mq * 16 + 4 * g];
#pragma unroll
        for (int mq = 0; mq < 2; ++mq)
#pragma unroll
            for (int nd = 0; nd < 4; ++nd)
#pragma unroll
                for (int r = 0; r < 4; ++r) o[mq][nd][r] *= sr[mq][r];

        // P A-frags: row = q = l16 (+16*mq), k = kv = kc*32+g*8+j (same swizzle)
        f16x8 pa[2][2];
#pragma unroll
        for (int mq = 0; mq < 2; ++mq) {
            int row = mq * 16 + l16;
            const char* base = (const char*)Pw + row * 128;
            int swz = (row & 7) << 4;
#pragma unroll
            for (int kc = 0; kc < 2; ++kc)
                pa[mq][kc] = *(const f16x8*)(base + ((kc * 64 + g * 16) ^ swz));
        }
        __builtin_amdgcn_s_setprio(1);
#pragma unroll
        for (int kc = 0; kc < 2; ++kc)
#pragma unroll
            for (int mq = 0; mq < 2; ++mq)
#pragma unroll
                for (int nd = 0; nd < 4; ++nd)
                    o[mq][nd] = __builtin_amdgcn_mfma_f32_16x16x32_f16(pa[mq][kc], vf[nd][kc], o[mq][nd], 0, 0, 0);
        __builtin_amdgcn_s_setprio(0);
        // keep next iteration's LDS writes from overlapping this iteration's reads
        asm volatile("s_waitcnt lgkmcnt(0)" ::: "memory");
        __builtin_amdgcn_sched_barrier(0);
    }

    // final 1/l, redistributed q->(g,r) via LDS
    if (lane < 16) { sclw[l16] = l_run[0]; sclw[16 + l16] = l_run[1]; }
    asm volatile("s_waitcnt lgkmcnt(0)" ::: "memory");
    __builtin_amdgcn_sched_barrier(0);
    int b = bh >> 3, h = bh & 7;
#pragma unroll
    for (int mq = 0; mq < 2; ++mq) {
        f32x4 lr = *(const f32x4*)&sclw[mq * 16 + 4 * g];
#pragma unroll
        for (int r = 0; r < 4; ++r) {
            float inv = 1.f / lr[r];
            int srow = q0 + mq * 16 + 4 * g + r;
#pragma unroll
            for (int nd = 0; nd < 4; ++nd)
                attn[(size_t)(b * Ss + srow) * E + h * 64 + nd * 16 + l16] = (f16)(o[mq][nd][r] * inv);
        }
    }
}

// ---------------- output projection + bias + residual ----------------
__global__ __launch_bounds__(256) void gemm_out_kernel(
    const f16* __restrict__ A, const f16* __restrict__ Wt,
    const float* __restrict__ bo, const float* __restrict__ emb,
    float* __restrict__ xout) {
    __shared__ f16 As[128 * LDP];
    __shared__ f16 Bs[128 * LDP];
    int tid = threadIdx.x;
    int m0 = blockIdx.x * 128, n0 = blockIdx.y * 128;
    int w = tid >> 6, lane = tid & 63;
    int wr = w >> 1, wc = w & 1;
    int lgrp = lane >> 4, l16 = lane & 15;
    f32x4 acc[4][4];
#pragma unroll
    for (int i = 0; i < 4; ++i)
#pragma unroll
        for (int j = 0; j < 4; ++j) acc[i][j] = (f32x4){0.f, 0.f, 0.f, 0.f};

    for (int kt = 0; kt < 16; ++kt) {
        int k0 = kt * 32;
        {
            int c = tid, row = c >> 2, seg = c & 3;
            *(f16x8*)&As[row * LDP + seg * 8] = *(const f16x8*)&A[(size_t)(m0 + row) * E + k0 + seg * 8];
            *(f16x8*)&Bs[row * LDP + seg * 8] = *(const f16x8*)&Wt[(size_t)(n0 + row) * E + k0 + seg * 8];
            c = tid + 256; row = c >> 2; seg = c & 3;
            *(f16x8*)&As[row * LDP + seg * 8] = *(const f16x8*)&A[(size_t)(m0 + row) * E + k0 + seg * 8];
            *(f16x8*)&Bs[row * LDP + seg * 8] = *(const f16x8*)&Wt[(size_t)(n0 + row) * E + k0 + seg * 8];
        }
        __syncthreads();
        f16x8 af[4], bfr[4];
#pragma unroll
        for (int mi = 0; mi < 4; ++mi)
            af[mi] = *(const f16x8*)&As[(wr * 64 + mi * 16 + l16) * LDP + lgrp * 8];
#pragma unroll
        for (int ni = 0; ni < 4; ++ni)
            bfr[ni] = *(const f16x8*)&Bs[(wc * 64 + ni * 16 + l16) * LDP + lgrp * 8];
#pragma unroll
        for (int mi = 0; mi < 4; ++mi)
#pragma unroll
            for (int ni = 0; ni < 4; ++ni)
                acc[mi][ni] = __builtin_amdgcn_mfma_f32_16x16x32_f16(af[mi], bfr[ni], acc[mi][ni], 0, 0, 0);
        __syncthreads();
    }
#pragma unroll
    for (int mi = 0; mi < 4; ++mi) {
#pragma unroll
        for (int ni = 0; ni < 4; ++ni) {
#pragma unroll
            for (int r = 0; r < 4; ++r) {
                int gm = m0 + wr * 64 + mi * 16 + lgrp * 4 + r;
                int gn = n0 + wc * 64 + ni * 16 + l16;
                size_t idx = (size_t)gm * E + gn;
                xout[idx] = acc[mi][ni][r] + bo[gn] + emb[idx];
            }
        }
    }
}

// ---------------- LayerNorm ----------------
__global__ __launch_bounds__(256) void ln_kernel(const float* __restrict__ x,
                                                 const float* __restrict__ g,
                                                 const float* __restrict__ b,
                                                 float* __restrict__ out) {
    int w = threadIdx.x >> 6, lane = threadIdx.x & 63;
    int row = blockIdx.x * 4 + w;
    const float* xr = x + (size_t)row * E;
    int c0 = lane * 8;
    float4 a = *(const float4*)&xr[c0];
    float4 c = *(const float4*)&xr[c0 + 4];
    float s = a.x + a.y + a.z + a.w + c.x + c.y + c.z + c.w;
    float q = a.x * a.x + a.y * a.y + a.z * a.z + a.w * a.w +
              c.x * c.x + c.y * c.y + c.z * c.z + c.w * c.w;
#pragma unroll
    for (int m = 1; m <= 32; m <<= 1) {
        s += __shfl_xor(s, m);
        q += __shfl_xor(q, m);
    }
    float mean = s * (1.f / 512.f);
    float var = q * (1.f / 512.f) - mean * mean;
    float rstd = rsqrtf(var + 1e-5f);
    float4 o1, o2;
    o1.x = (a.x - mean) * rstd * g[c0 + 0] + b[c0 + 0];
    o1.y = (a.y - mean) * rstd * g[c0 + 1] + b[c0 + 1];
    o1.z = (a.z - mean) * rstd * g[c0 + 2] + b[c0 + 2];
    o1.w = (a.w - mean) * rstd * g[c0 + 3] + b[c0 + 3];
    o2.x = (c.x - mean) * rstd * g[c0 + 4] + b[c0 + 4];
    o2.y = (c.y - mean) * rstd * g[c0 + 5] + b[c0 + 5];
    o2.z = (c.z - mean) * rstd * g[c0 + 6] + b[c0 + 6];
    o2.w = (c.w - mean) * rstd * g[c0 + 7] + b[c0 + 7];
    *(float4*)&out[(size_t)row * E + c0] = o1;
    *(float4*)&out[(size_t)row * E + c0 + 4] = o2;
}

extern "C" void kernel_launch(void* const* d_in, const int* in_sizes, int n_in,
                              void* d_out, int out_size, void* d_ws, size_t ws_size,
                              hipStream_t stream) {
    const float* emb = (const float*)d_in[0];
    const float* wq = (const float*)d_in[1];
    const float* bq = (const float*)d_in[2];
    const float* wk = (const float*)d_in[3];
    const float* bk = (const float*)d_in[4];
    const float* wv = (const float*)d_in[5];
    const float* bv = (const float*)d_in[6];
    const float* wo = (const float*)d_in[7];
    const float* bo = (const float*)d_in[8];
    const float* ln_g = (const float*)d_in[9];
    const float* ln_b = (const float*)d_in[10];
    float* out = (float*)d_out;

    char* ws = (char*)d_ws;
    f16* embh  = (f16*)(ws);
    f16* wtqkv = (f16*)(ws + 8388608);
    f16* wto   = (f16*)(ws + 9961472);
    f16* Qb    = (f16*)(ws + 10485760);
    f16* Kb    = (f16*)(ws + 18874368);
    f16* Vt    = (f16*)(ws + 27262976);
    f16* attnb = (f16*)(ws + 35651584);
    float* xbuf = (float*)(ws + 10485760);  // overlaps Qb+Kb (dead after attention)

    cvt_emb_kernel<<<dim3(2048), dim3(256), 0, stream>>>(emb, embh);
    cvt_w_kernel<<<dim3(2048), dim3(64), 0, stream>>>(wq, wk, wv, wo, wtqkv, wto);
    gemm_qkv_kernel<<<dim3(64, 12), dim3(256), 0, stream>>>(embh, wtqkv, bq, bk, bv, Qb, Kb, Vt);
    attn_kernel<<<dim3(2048), dim3(64), 0, stream>>>(Qb, Kb, Vt, attnb);
    gemm_out_kernel<<<dim3(64, 4), dim3(256), 0, stream>>>(attnb, wto, bo, emb, xbuf);
    ln_kernel<<<dim3(2048), dim3(256), 0, stream>>>(xbuf, ln_g, ln_b, out);
}

// Round 8
// 302.698 us; speedup vs baseline: 1.2987x; 1.0361x over previous
//
#include <hip/hip_runtime.h>

#define E 512
#define Hh 8
#define Dd 64
#define Ss 4096
#define Bb 2

typedef _Float16 f16;
typedef __attribute__((ext_vector_type(4))) _Float16 f16x4;
typedef __attribute__((ext_vector_type(8))) _Float16 f16x8;
typedef __attribute__((ext_vector_type(4))) float f32x4;

// ---------------- convert emb fp32 -> f16 ----------------
__global__ __launch_bounds__(256) void cvt_emb_kernel(const float* __restrict__ in,
                                                      f16* __restrict__ out) {
    int i = (blockIdx.x * 256 + threadIdx.x) * 8;
    float4 a = *(const float4*)(in + i);
    float4 b = *(const float4*)(in + i + 4);
    f16x8 o;
    o[0] = (f16)a.x; o[1] = (f16)a.y; o[2] = (f16)a.z; o[3] = (f16)a.w;
    o[4] = (f16)b.x; o[5] = (f16)b.y; o[6] = (f16)b.z; o[7] = (f16)b.w;
    *(f16x8*)(out + i) = o;
}

// ------------- transpose weights -> Wt[n][k] f16 -------------
__global__ __launch_bounds__(64) void cvt_w_kernel(const float* __restrict__ wq,
                                                   const float* __restrict__ wk,
                                                   const float* __restrict__ wv,
                                                   const float* __restrict__ wo,
                                                   f16* __restrict__ wtqkv,
                                                   f16* __restrict__ wto) {
    int n = blockIdx.x;      // 0..2047
    int t = threadIdx.x;     // 0..63
    const float* src;
    f16* dst;
    int col = n & 511;
    if (n < 1536) {
        int which = n >> 9;
        src = (which == 0) ? wq : (which == 1) ? wk : wv;
        dst = wtqkv + (size_t)n * E;
    } else {
        src = wo;
        dst = wto + (size_t)(n - 1536) * E;
    }
    int k0 = t * 8;
    f16x8 o;
#pragma unroll
    for (int j = 0; j < 8; ++j) o[j] = (f16)src[(size_t)(k0 + j) * E + col];
    *(f16x8*)(dst + k0) = o;
}

// ---------------- QKV projection GEMM ----------------
#define LDP 40

__global__ __launch_bounds__(256) void gemm_qkv_kernel(
    const f16* __restrict__ A, const f16* __restrict__ Wt,
    const float* __restrict__ bq, const float* __restrict__ bk,
    const float* __restrict__ bv,
    f16* __restrict__ Qb, f16* __restrict__ Kb, f16* __restrict__ Vt) {
    __shared__ f16 As[128 * LDP];
    __shared__ f16 Bs[128 * LDP];
    int tid = threadIdx.x;
    int m0 = blockIdx.x * 128, n0 = blockIdx.y * 128;
    int w = tid >> 6, lane = tid & 63;
    int wr = w >> 1, wc = w & 1;
    int lgrp = lane >> 4, l16 = lane & 15;
    f32x4 acc[4][4];
#pragma unroll
    for (int i = 0; i < 4; ++i)
#pragma unroll
        for (int j = 0; j < 4; ++j) acc[i][j] = (f32x4){0.f, 0.f, 0.f, 0.f};

    for (int kt = 0; kt < 16; ++kt) {
        int k0 = kt * 32;
        {
            int c = tid, row = c >> 2, seg = c & 3;
            *(f16x8*)&As[row * LDP + seg * 8] = *(const f16x8*)&A[(size_t)(m0 + row) * E + k0 + seg * 8];
            *(f16x8*)&Bs[row * LDP + seg * 8] = *(const f16x8*)&Wt[(size_t)(n0 + row) * E + k0 + seg * 8];
            c = tid + 256; row = c >> 2; seg = c & 3;
            *(f16x8*)&As[row * LDP + seg * 8] = *(const f16x8*)&A[(size_t)(m0 + row) * E + k0 + seg * 8];
            *(f16x8*)&Bs[row * LDP + seg * 8] = *(const f16x8*)&Wt[(size_t)(n0 + row) * E + k0 + seg * 8];
        }
        __syncthreads();
        f16x8 af[4], bfr[4];
#pragma unroll
        for (int mi = 0; mi < 4; ++mi)
            af[mi] = *(const f16x8*)&As[(wr * 64 + mi * 16 + l16) * LDP + lgrp * 8];
#pragma unroll
        for (int ni = 0; ni < 4; ++ni)
            bfr[ni] = *(const f16x8*)&Bs[(wc * 64 + ni * 16 + l16) * LDP + lgrp * 8];
#pragma unroll
        for (int mi = 0; mi < 4; ++mi)
#pragma unroll
            for (int ni = 0; ni < 4; ++ni)
                acc[mi][ni] = __builtin_amdgcn_mfma_f32_16x16x32_f16(af[mi], bfr[ni], acc[mi][ni], 0, 0, 0);
        __syncthreads();
    }
#pragma unroll
    for (int mi = 0; mi < 4; ++mi) {
#pragma unroll
        for (int ni = 0; ni < 4; ++ni) {
#pragma unroll
            for (int r = 0; r < 4; ++r) {
                int gm = m0 + wr * 64 + mi * 16 + lgrp * 4 + r;
                int gn = n0 + wc * 64 + ni * 16 + l16;
                int which = gn >> 9, e = gn & 511;
                int h = e >> 6, d = e & 63;
                int b = gm >> 12, s = gm & 4095;
                float v = acc[mi][ni][r];
                if (which == 0) {
                    // fold 1/sqrt(64) AND log2(e) into Q so attention works in exp2 domain
                    v = (v + bq[e]) * 0.180336880111f;
                    Qb[(size_t)((b * Hh + h) * Ss + s) * Dd + d] = (f16)v;
                } else if (which == 1) {
                    v += bk[e];
                    Kb[(size_t)((b * Hh + h) * Ss + s) * Dd + d] = (f16)v;
                } else {
                    v += bv[e];
                    Vt[(size_t)((b * Hh + h) * Dd + d) * Ss + s] = (f16)v;
                }
            }
        }
    }
}

// ---------------- causal flash attention ----------------
// grid (2048), 1 wave/block. idx -> tile = 127-(idx>>4) (LPT), bh = (idx&7)*2 + ((idx>>3)&1)
// so each XCD (round-robin idx&7) touches only 2 heads = 2MB K/V -> L2-resident.
// Swapped QK^T: mfma(K,Q) -> lane holds q=l16 (+16nf), kv=mf*16+4g+r.
// Defer-max (THR=8, exp2 domain): cross-lane max reduce + O-rescale only when the
// running max grows; per-lane partial l sums, reduced ONCE after the loop.
__global__ __launch_bounds__(64) void attn_kernel(const f16* __restrict__ Qb,
                                                  const f16* __restrict__ Kb,
                                                  const f16* __restrict__ Vt,
                                                  f16* __restrict__ attn) {
    __shared__ __align__(16) f16 Pw[32 * 64];
    __shared__ __align__(16) float sclw[32];
    int lane = threadIdx.x;
    int g = lane >> 4, l16 = lane & 15;
    int idx = blockIdx.x;
    int bh = (idx & 7) * 2 + ((idx >> 3) & 1);
    int tile = 127 - (idx >> 4);   // heavy tiles dispatch first
    int q0 = tile * 32;
    const f16* Qp = Qb + (size_t)bh * Ss * Dd;
    const f16* Kp = Kb + (size_t)bh * Ss * Dd;
    const f16* Vp = Vt + (size_t)bh * Dd * Ss;
    const float THR = 8.0f;   // exp2-domain defer threshold: p <= 2^8, f16-safe

    f16x8 qf[2][2];
#pragma unroll
    for (int nf = 0; nf < 2; ++nf)
#pragma unroll
        for (int kc = 0; kc < 2; ++kc)
            qf[nf][kc] = *(const f16x8*)&Qp[(size_t)(q0 + nf * 16 + l16) * Dd + kc * 32 + g * 8];

    f32x4 o[2][4];
#pragma unroll
    for (int mq = 0; mq < 2; ++mq)
#pragma unroll
        for (int nd = 0; nd < 4; ++nd) o[mq][nd] = (f32x4){0.f, 0.f, 0.f, 0.f};
    float m_run[2] = {-1e30f, -1e30f};
    float l_part[2] = {0.f, 0.f};   // per-lane partial sum over this lane's kv slots

    const int count = (tile >> 1) + 1;
    for (int t = 0; t < count; ++t) {
        int n0 = t << 6;
        bool last = (t == count - 1);

        f16x8 kf[4][2];
#pragma unroll
        for (int mf = 0; mf < 4; ++mf)
#pragma unroll
            for (int kc = 0; kc < 2; ++kc)
                kf[mf][kc] = *(const f16x8*)&Kp[(size_t)(n0 + mf * 16 + l16) * Dd + kc * 32 + g * 8];

        f32x4 s_[4][2];
#pragma unroll
        for (int mf = 0; mf < 4; ++mf)
#pragma unroll
            for (int nf = 0; nf < 2; ++nf) s_[mf][nf] = (f32x4){0.f, 0.f, 0.f, 0.f};
        __builtin_amdgcn_s_setprio(1);
#pragma unroll
        for (int kc = 0; kc < 2; ++kc)
#pragma unroll
            for (int mf = 0; mf < 4; ++mf)
#pragma unroll
                for (int nf = 0; nf < 2; ++nf)
                    s_[mf][nf] = __builtin_amdgcn_mfma_f32_16x16x32_f16(kf[mf][kc], qf[nf][kc], s_[mf][nf], 0, 0, 0);
        __builtin_amdgcn_s_setprio(0);

        // V for PV, issued early so L2 latency hides under softmax
        f16x8 vf[4][2];
#pragma unroll
        for (int nd = 0; nd < 4; ++nd)
#pragma unroll
            for (int kc = 0; kc < 2; ++kc)
                vf[nd][kc] = *(const f16x8*)&Vp[(size_t)(nd * 16 + l16) * Ss + n0 + kc * 32 + g * 8];

        if (last) {
#pragma unroll
            for (int mf = 0; mf < 4; ++mf)
#pragma unroll
                for (int nf = 0; nf < 2; ++nf)
#pragma unroll
                    for (int r = 0; r < 4; ++r) {
                        int kv = n0 + mf * 16 + 4 * g + r;
                        int qq = q0 + nf * 16 + l16;
                        if (kv > qq) s_[mf][nf][r] = -INFINITY;
                    }
        }

        // per-lane tree max over 16 in-lane values, per nf
        float tmax[2];
#pragma unroll
        for (int nf = 0; nf < 2; ++nf) {
            float a0 = fmaxf(fmaxf(s_[0][nf][0], s_[0][nf][1]), fmaxf(s_[0][nf][2], s_[0][nf][3]));
            float a1 = fmaxf(fmaxf(s_[1][nf][0], s_[1][nf][1]), fmaxf(s_[1][nf][2], s_[1][nf][3]));
            float a2 = fmaxf(fmaxf(s_[2][nf][0], s_[2][nf][1]), fmaxf(s_[2][nf][2], s_[2][nf][3]));
            float a3 = fmaxf(fmaxf(s_[3][nf][0], s_[3][nf][1]), fmaxf(s_[3][nf][2], s_[3][nf][3]));
            tmax[nf] = fmaxf(fmaxf(a0, a1), fmaxf(a2, a3));
        }

        // defer-max: only when the running max actually grows past THR
        if (__any((tmax[0] > m_run[0] + THR) || (tmax[1] > m_run[1] + THR))) {
            float sc[2];
#pragma unroll
            for (int nf = 0; nf < 2; ++nf) {
                float mx = fmaxf(tmax[nf], __shfl_xor(tmax[nf], 16));
                mx = fmaxf(mx, __shfl_xor(mx, 32));
                float mn = fmaxf(m_run[nf], mx);
                sc[nf] = __builtin_amdgcn_exp2f(m_run[nf] - mn);
                m_run[nf] = mn;
                l_part[nf] *= sc[nf];   // per-lane, same q as sc -> direct
            }
            if (lane < 16) { sclw[l16] = sc[0]; sclw[16 + l16] = sc[1]; }
            asm volatile("s_waitcnt lgkmcnt(0)" ::: "memory");
            __builtin_amdgcn_sched_barrier(0);
            f32x4 sr[2];
#pragma unroll
            for (int mq = 0; mq < 2; ++mq) sr[mq] = *(const f32x4*)&sclw[mq * 16 + 4 * g];
#pragma unroll
            for (int mq = 0; mq < 2; ++mq)
#pragma unroll
                for (int nd = 0; nd < 4; ++nd)
#pragma unroll
                    for (int r = 0; r < 4; ++r) o[mq][nd][r] *= sr[mq][r];
        }

        // p = exp2(s - m), per-lane partial sums (no cross-lane reduce)
#pragma unroll
        for (int nf = 0; nf < 2; ++nf) {
            float mrun = m_run[nf];
            float ps[4];
#pragma unroll
            for (int mf = 0; mf < 4; ++mf) {
                float p0 = __builtin_amdgcn_exp2f(s_[mf][nf][0] - mrun);
                float p1 = __builtin_amdgcn_exp2f(s_[mf][nf][1] - mrun);
                float p2 = __builtin_amdgcn_exp2f(s_[mf][nf][2] - mrun);
                float p3 = __builtin_amdgcn_exp2f(s_[mf][nf][3] - mrun);
                s_[mf][nf][0] = p0; s_[mf][nf][1] = p1;
                s_[mf][nf][2] = p2; s_[mf][nf][3] = p3;
                ps[mf] = (p0 + p1) + (p2 + p3);
            }
            l_part[nf] += (ps[0] + ps[1]) + (ps[2] + ps[3]);
        }

        // P -> LDS [row=q 32][col=kv 64] f16, XOR-swizzled
#pragma unroll
        for (int nf = 0; nf < 2; ++nf) {
            int row = nf * 16 + l16;
            char* base = (char*)Pw + row * 128;
            int swz = (row & 7) << 4;
#pragma unroll
            for (int mf = 0; mf < 4; ++mf) {
                f16x4 ph;
#pragma unroll
                for (int r = 0; r < 4; ++r) ph[r] = (f16)s_[mf][nf][r];
                *(f16x4*)(base + ((mf * 32 + g * 8) ^ swz)) = ph;
            }
        }
        asm volatile("s_waitcnt lgkmcnt(0)" ::: "memory");
        __builtin_amdgcn_sched_barrier(0);

        f16x8 pa[2][2];
#pragma unroll
        for (int mq = 0; mq < 2; ++mq) {
            int row = mq * 16 + l16;
            const char* base = (const char*)Pw + row * 128;
            int swz = (row & 7) << 4;
#pragma unroll
            for (int kc = 0; kc < 2; ++kc)
                pa[mq][kc] = *(const f16x8*)(base + ((kc * 64 + g * 16) ^ swz));
        }
        __builtin_amdgcn_s_setprio(1);
#pragma unroll
        for (int kc = 0; kc < 2; ++kc)
#pragma unroll
            for (int mq = 0; mq < 2; ++mq)
#pragma unroll
                for (int nd = 0; nd < 4; ++nd)
                    o[mq][nd] = __builtin_amdgcn_mfma_f32_16x16x32_f16(pa[mq][kc], vf[nd][kc], o[mq][nd], 0, 0, 0);
        __builtin_amdgcn_s_setprio(0);
        // no trailing fence: same-wave DS ops are pipe-ordered (next iter's writes
        // cannot bypass this iter's reads), and the compiler inserts data waits.
    }

    // final l: reduce partials across the 4 g-lanes, once
    float l0 = l_part[0], l1 = l_part[1];
    l0 += __shfl_xor(l0, 16); l0 += __shfl_xor(l0, 32);
    l1 += __shfl_xor(l1, 16); l1 += __shfl_xor(l1, 32);
    if (lane < 16) { sclw[l16] = l0; sclw[16 + l16] = l1; }
    asm volatile("s_waitcnt lgkmcnt(0)" ::: "memory");
    __builtin_amdgcn_sched_barrier(0);
    int b = bh >> 3, h = bh & 7;
#pragma unroll
    for (int mq = 0; mq < 2; ++mq) {
        f32x4 lr = *(const f32x4*)&sclw[mq * 16 + 4 * g];
#pragma unroll
        for (int r = 0; r < 4; ++r) {
            float inv = 1.f / lr[r];
            int srow = q0 + mq * 16 + 4 * g + r;
#pragma unroll
            for (int nd = 0; nd < 4; ++nd)
                attn[(size_t)(b * Ss + srow) * E + h * 64 + nd * 16 + l16] = (f16)(o[mq][nd][r] * inv);
        }
    }
}

// ---------------- output projection + bias + residual ----------------
__global__ __launch_bounds__(256) void gemm_out_kernel(
    const f16* __restrict__ A, const f16* __restrict__ Wt,
    const float* __restrict__ bo, const float* __restrict__ emb,
    float* __restrict__ xout) {
    __shared__ f16 As[128 * LDP];
    __shared__ f16 Bs[128 * LDP];
    int tid = threadIdx.x;
    int m0 = blockIdx.x * 128, n0 = blockIdx.y * 128;
    int w = tid >> 6, lane = tid & 63;
    int wr = w >> 1, wc = w & 1;
    int lgrp = lane >> 4, l16 = lane & 15;
    f32x4 acc[4][4];
#pragma unroll
    for (int i = 0; i < 4; ++i)
#pragma unroll
        for (int j = 0; j < 4; ++j) acc[i][j] = (f32x4){0.f, 0.f, 0.f, 0.f};

    for (int kt = 0; kt < 16; ++kt) {
        int k0 = kt * 32;
        {
            int c = tid, row = c >> 2, seg = c & 3;
            *(f16x8*)&As[row * LDP + seg * 8] = *(const f16x8*)&A[(size_t)(m0 + row) * E + k0 + seg * 8];
            *(f16x8*)&Bs[row * LDP + seg * 8] = *(const f16x8*)&Wt[(size_t)(n0 + row) * E + k0 + seg * 8];
            c = tid + 256; row = c >> 2; seg = c & 3;
            *(f16x8*)&As[row * LDP + seg * 8] = *(const f16x8*)&A[(size_t)(m0 + row) * E + k0 + seg * 8];
            *(f16x8*)&Bs[row * LDP + seg * 8] = *(const f16x8*)&Wt[(size_t)(n0 + row) * E + k0 + seg * 8];
        }
        __syncthreads();
        f16x8 af[4], bfr[4];
#pragma unroll
        for (int mi = 0; mi < 4; ++mi)
            af[mi] = *(const f16x8*)&As[(wr * 64 + mi * 16 + l16) * LDP + lgrp * 8];
#pragma unroll
        for (int ni = 0; ni < 4; ++ni)
            bfr[ni] = *(const f16x8*)&Bs[(wc * 64 + ni * 16 + l16) * LDP + lgrp * 8];
#pragma unroll
        for (int mi = 0; mi < 4; ++mi)
#pragma unroll
            for (int ni = 0; ni < 4; ++ni)
                acc[mi][ni] = __builtin_amdgcn_mfma_f32_16x16x32_f16(af[mi], bfr[ni], acc[mi][ni], 0, 0, 0);
        __syncthreads();
    }
#pragma unroll
    for (int mi = 0; mi < 4; ++mi) {
#pragma unroll
        for (int ni = 0; ni < 4; ++ni) {
#pragma unroll
            for (int r = 0; r < 4; ++r) {
                int gm = m0 + wr * 64 + mi * 16 + lgrp * 4 + r;
                int gn = n0 + wc * 64 + ni * 16 + l16;
                size_t idx = (size_t)gm * E + gn;
                xout[idx] = acc[mi][ni][r] + bo[gn] + emb[idx];
            }
        }
    }
}

// ---------------- LayerNorm ----------------
__global__ __launch_bounds__(256) void ln_kernel(const float* __restrict__ x,
                                                 const float* __restrict__ g,
                                                 const float* __restrict__ b,
                                                 float* __restrict__ out) {
    int w = threadIdx.x >> 6, lane = threadIdx.x & 63;
    int row = blockIdx.x * 4 + w;
    const float* xr = x + (size_t)row * E;
    int c0 = lane * 8;
    float4 a = *(const float4*)&xr[c0];
    float4 c = *(const float4*)&xr[c0 + 4];
    float s = a.x + a.y + a.z + a.w + c.x + c.y + c.z + c.w;
    float q = a.x * a.x + a.y * a.y + a.z * a.z + a.w * a.w +
              c.x * c.x + c.y * c.y + c.z * c.z + c.w * c.w;
#pragma unroll
    for (int m = 1; m <= 32; m <<= 1) {
        s += __shfl_xor(s, m);
        q += __shfl_xor(q, m);
    }
    float mean = s * (1.f / 512.f);
    float var = q * (1.f / 512.f) - mean * mean;
    float rstd = rsqrtf(var + 1e-5f);
    float4 o1, o2;
    o1.x = (a.x - mean) * rstd * g[c0 + 0] + b[c0 + 0];
    o1.y = (a.y - mean) * rstd * g[c0 + 1] + b[c0 + 1];
    o1.z = (a.z - mean) * rstd * g[c0 + 2] + b[c0 + 2];
    o1.w = (a.w - mean) * rstd * g[c0 + 3] + b[c0 + 3];
    o2.x = (c.x - mean) * rstd * g[c0 + 4] + b[c0 + 4];
    o2.y = (c.y - mean) * rstd * g[c0 + 5] + b[c0 + 5];
    o2.z = (c.z - mean) * rstd * g[c0 + 6] + b[c0 + 6];
    o2.w = (c.w - mean) * rstd * g[c0 + 7] + b[c0 + 7];
    *(float4*)&out[(size_t)row * E + c0] = o1;
    *(float4*)&out[(size_t)row * E + c0 + 4] = o2;
}

extern "C" void kernel_launch(void* const* d_in, const int* in_sizes, int n_in,
                              void* d_out, int out_size, void* d_ws, size_t ws_size,
                              hipStream_t stream) {
    const float* emb = (const float*)d_in[0];
    const float* wq = (const float*)d_in[1];
    const float* bq = (const float*)d_in[2];
    const float* wk = (const float*)d_in[3];
    const float* bk = (const float*)d_in[4];
    const float* wv = (const float*)d_in[5];
    const float* bv = (const float*)d_in[6];
    const float* wo = (const float*)d_in[7];
    const float* bo = (const float*)d_in[8];
    const float* ln_g = (const float*)d_in[9];
    const float* ln_b = (const float*)d_in[10];
    float* out = (float*)d_out;

    char* ws = (char*)d_ws;
    f16* embh  = (f16*)(ws);
    f16* wtqkv = (f16*)(ws + 8388608);
    f16* wto   = (f16*)(ws + 9961472);
    f16* Qb    = (f16*)(ws + 10485760);
    f16* Kb    = (f16*)(ws + 18874368);
    f16* Vt    = (f16*)(ws + 27262976);
    f16* attnb = (f16*)(ws + 35651584);
    float* xbuf = (float*)(ws + 10485760);  // overlaps Qb+Kb (dead after attention)

    cvt_emb_kernel<<<dim3(2048), dim3(256), 0, stream>>>(emb, embh);
    cvt_w_kernel<<<dim3(2048), dim3(64), 0, stream>>>(wq, wk, wv, wo, wtqkv, wto);
    gemm_qkv_kernel<<<dim3(64, 12), dim3(256), 0, stream>>>(embh, wtqkv, bq, bk, bv, Qb, Kb, Vt);
    attn_kernel<<<dim3(2048), dim3(64), 0, stream>>>(Qb, Kb, Vt, attnb);
    gemm_out_kernel<<<dim3(64, 4), dim3(256), 0, stream>>>(attnb, wto, bo, emb, xbuf);
    ln_kernel<<<dim3(2048), dim3(256), 0, stream>>>(xbuf, ln_g, ln_b, out);
}